// Round 3
// baseline (547.347 us; speedup 1.0000x reference)
//
#include <hip/hip_runtime.h>
#include <hip/hip_bf16.h>

// N=8192, D_IN=128, H=64, C=40, E=262144, TAU=0.25, T=4 -> 16 steps.
constexpr int N_   = 8192;
constexpr int DIN_ = 128;
constexpr int H_   = 64;
constexpr int C_   = 40;
constexpr int STEPS_ = 16;
#define TAU_ 0.25f

// ---------------- front-end (unchanged from R2) ----------------

__global__ __launch_bounds__(256) void enc_k(const float* __restrict__ xin,
    const float* __restrict__ w, const float* __restrict__ b,
    float* __restrict__ x0)
{
    int wid  = (blockIdx.x * 256 + threadIdx.x) >> 6;
    int lane = threadIdx.x & 63;
    int r0 = wid * 4;
    if (r0 >= N_) return;
    const float* xr = xin + (size_t)r0 * DIN_;
    float bv = b[lane];
    float a0 = bv, a1 = bv, a2 = bv, a3 = bv;
    for (int k = 0; k < DIN_; ++k) {
        float wv = w[k * H_ + lane];
        a0 = fmaf(xr[k],            wv, a0);
        a1 = fmaf(xr[DIN_ + k],     wv, a1);
        a2 = fmaf(xr[2 * DIN_ + k], wv, a2);
        a3 = fmaf(xr[3 * DIN_ + k], wv, a3);
    }
    float* o = x0 + (size_t)r0 * H_ + lane;
    o[0] = a0; o[H_] = a1; o[2 * H_] = a2; o[3 * H_] = a3;
}

__global__ __launch_bounds__(256) void kq_k(const float* __restrict__ x0,
    const float* __restrict__ wk, const float* __restrict__ kb,
    const float* __restrict__ wq, const float* __restrict__ qb,
    float* __restrict__ kx, float* __restrict__ qx)
{
    int wid  = (blockIdx.x * 256 + threadIdx.x) >> 6;
    int lane = threadIdx.x & 63;
    int r0 = wid * 4;
    if (r0 >= N_) return;
    const float* xr = x0 + (size_t)r0 * H_;
    float kbv = kb[lane], qbv = qb[lane];
    float ak0 = kbv, ak1 = kbv, ak2 = kbv, ak3 = kbv;
    float aq0 = qbv, aq1 = qbv, aq2 = qbv, aq3 = qbv;
    for (int k = 0; k < H_; ++k) {
        float wkv = wk[k * H_ + lane];
        float wqv = wq[k * H_ + lane];
        float x0v = xr[k], x1v = xr[H_ + k], x2v = xr[2 * H_ + k], x3v = xr[3 * H_ + k];
        ak0 = fmaf(x0v, wkv, ak0);  aq0 = fmaf(x0v, wqv, aq0);
        ak1 = fmaf(x1v, wkv, ak1);  aq1 = fmaf(x1v, wqv, aq1);
        ak2 = fmaf(x2v, wkv, ak2);  aq2 = fmaf(x2v, wqv, aq2);
        ak3 = fmaf(x3v, wkv, ak3);  aq3 = fmaf(x3v, wqv, aq3);
    }
    float* ok = kx + (size_t)r0 * H_ + lane;
    float* oq = qx + (size_t)r0 * H_ + lane;
    ok[0] = ak0; ok[H_] = ak1; ok[2 * H_] = ak2; ok[3 * H_] = ak3;
    oq[0] = aq0; oq[H_] = aq1; oq[2 * H_] = aq2; oq[3 * H_] = aq3;
}

__global__ __launch_bounds__(256) void count_k(const int2* __restrict__ edges,
    int* __restrict__ deg, int E)
{
    int e = blockIdx.x * 256 + threadIdx.x;
    if (e >= E) return;
    atomicAdd(&deg[edges[e].x], 1);
}

__global__ __launch_bounds__(256) void scan_k(const int* __restrict__ deg,
    int* __restrict__ row_ptr, int* __restrict__ row_fill)
{
    __shared__ int partial[257];
    int t = threadIdx.x;
    const int chunk = N_ / 256;
    int base = t * chunk;
    int s = 0;
    for (int i = 0; i < chunk; ++i) s += deg[base + i];
    partial[t] = s;
    __syncthreads();
    if (t == 0) {
        int run = 0;
        for (int i = 0; i < 256; ++i) { int tmp = partial[i]; partial[i] = run; run += tmp; }
        partial[256] = run;
    }
    __syncthreads();
    int run = partial[t];
    for (int i = 0; i < chunk; ++i) {
        row_ptr[base + i] = run;
        row_fill[base + i] = run;
        run += deg[base + i];
    }
    if (t == 255) row_ptr[N_] = run;
}

__global__ __launch_bounds__(256) void score_place_k(const int2* __restrict__ edges,
    const float* __restrict__ kx, const float* __restrict__ qx,
    int* __restrict__ row_fill, int* __restrict__ csr_v, float* __restrict__ csr_w, int E)
{
    int t  = blockIdx.x * 256 + threadIdx.x;
    int eg = t >> 4;
    int sl = t & 15;
    if (eg >= E) return;
    int2 uv = edges[eg];
    float4 a = ((const float4*)(kx + (size_t)uv.x * H_))[sl];
    float4 b = ((const float4*)(qx + (size_t)uv.y * H_))[sl];
    float d = a.x * b.x + a.y * b.y + a.z * b.z + a.w * b.w;
    d += __shfl_xor(d, 1);
    d += __shfl_xor(d, 2);
    d += __shfl_xor(d, 4);
    d += __shfl_xor(d, 8);
    if (sl == 0) {
        float w = expf(d * (1.0f / (float)H_));
        int pos = atomicAdd(&row_fill[uv.x], 1);
        csr_v[pos] = uv.y;
        csr_w[pos] = w;
    }
}

__global__ __launch_bounds__(256) void dedup_k(const int* __restrict__ row_ptr,
    const int* __restrict__ csr_v, const float* __restrict__ csr_w,
    int2* __restrict__ vw)
{
    __shared__ unsigned int bm[4][256];   // 8192 bits per wave
    int wv   = threadIdx.x >> 6;
    int lane = threadIdx.x & 63;
    int row  = blockIdx.x * 4 + wv;
    unsigned int* b = bm[wv];
    for (int i = lane; i < 256; i += 64) b[i] = 0;
    __syncthreads();
    int p0 = row_ptr[row], p1 = row_ptr[row + 1];
    float wsum = 0.f;
    for (int p = p0 + lane; p < p1; p += 64) {
        int v = csr_v[p];
        unsigned int m = 1u << (v & 31);
        unsigned int old = atomicOr(&b[v >> 5], m);
        float w = (old & m) ? 0.0f : csr_w[p];
        vw[p] = make_int2(v, __float_as_int(w));
        wsum += w;
    }
    #pragma unroll
    for (int off = 1; off < 64; off <<= 1) wsum += __shfl_xor(wsum, off);
    if (p0 == p1) return;                  // empty row
    float scale = TAU_ / wsum;
    for (int p = p0 + lane; p < p1; p += 64) {
        int2 e = vw[p];
        e.y = __float_as_int(__int_as_float(e.y) * scale);
        vw[p] = e;
    }
}

// ---------------- fused 16-step propagation + decode ----------------
// Persistent kernel: 256 blocks x 1024 threads. 256 blocks <= 256 CUs and
// __launch_bounds__(1024,4) caps VGPR so each CU hosts >= 1 block => all
// blocks co-resident => software grid barrier is deadlock-free.
// Barrier: cumulative arrival counter (256 far-atomics), relaxed spin,
// __threadfence() for cross-XCD release/acquire.
__global__ __launch_bounds__(1024, 4) void steps_k(
    float* __restrict__ x0buf, float* __restrict__ xbbuf,
    const int* __restrict__ row_ptr, const int2* __restrict__ vw,
    const float* __restrict__ dw, const float* __restrict__ db,
    float* __restrict__ out, int* __restrict__ bar)
{
    const int NBLK = 256;
    int wid  = (blockIdx.x << 4) + (threadIdx.x >> 6);   // 0..4095
    int lane = threadIdx.x & 63;

    float* xa = x0buf;
    float* xo = xbbuf;
    for (int s = 0; s < STEPS_; ++s) {
        #pragma unroll
        for (int rr = 0; rr < 2; ++rr) {
            int row = wid * 2 + rr;
            int p0 = row_ptr[row], p1 = row_ptr[row + 1];
            float acc = (1.0f - TAU_) * xa[(size_t)row * H_ + lane];
            for (int base = p0; base < p1; base += 64) {
                int rem = p1 - base;                 // wave-uniform, > 0
                int2 e = (lane < rem) ? vw[base + lane] : make_int2(0, 0);
                #pragma unroll
                for (int i = 0; i < 64; i += 16) {
                    if (i < rem) {                   // uniform branch
                        #pragma unroll
                        for (int j = 0; j < 16; ++j) {
                            int   v = __shfl(e.x, i + j);
                            float w = __int_as_float(__shfl(e.y, i + j));
                            acc = fmaf(w, xa[(size_t)v * H_ + lane], acc);
                        }
                    }
                }
            }
            xo[(size_t)row * H_ + lane] = acc;
        }
        { float* t = xa; xa = xo; xo = t; }

        if (s < STEPS_ - 1) {                        // no barrier after last step:
            __syncthreads();                          // decode reads only this wave's rows
            if (threadIdx.x == 0) {
                __threadfence();                      // release our x writes device-wide
                __hip_atomic_fetch_add(bar, 1, __ATOMIC_RELAXED, __HIP_MEMORY_SCOPE_AGENT);
                int target = (s + 1) * NBLK;
                while (__hip_atomic_load(bar, __ATOMIC_RELAXED, __HIP_MEMORY_SCOPE_AGENT) < target) {
                    __builtin_amdgcn_s_sleep(1);
                }
                __threadfence();                      // acquire others' x writes
            }
            __syncthreads();
        }
    }

    // decode: out[row] = x[row] @ dec_w + dec_b. xa = final x; this wave wrote
    // its own rows' values (all 64 cols), so reads are same-wave RAW via L1.
    if (lane < C_) {
        #pragma unroll
        for (int rr = 0; rr < 2; ++rr) {
            int row = wid * 2 + rr;
            const float* xr = xa + (size_t)row * H_;
            float a = db[lane];
            for (int k = 0; k < H_; ++k)
                a = fmaf(xr[k], dw[k * C_ + lane], a);
            out[(size_t)row * C_ + lane] = a;
        }
    }
}

// out = x @ dec_w + dec_b  (kept for reference; decode now fused in steps_k)

extern "C" void kernel_launch(void* const* d_in, const int* in_sizes, int n_in,
                              void* d_out, int out_size, void* d_ws, size_t ws_size,
                              hipStream_t stream)
{
    const float* x_in  = (const float*)d_in[0];
    const float* enc_w = (const float*)d_in[1];
    const float* enc_b = (const float*)d_in[2];
    const float* wk_w  = (const float*)d_in[3];
    const float* wk_b  = (const float*)d_in[4];
    const float* wq_w  = (const float*)d_in[5];
    const float* wq_b  = (const float*)d_in[6];
    const float* dec_w = (const float*)d_in[7];
    const float* dec_b = (const float*)d_in[8];
    const int2*  edges = (const int2*)d_in[9];
    const int E = in_sizes[9] / 2;   // 262144
    float* out = (float*)d_out;

    char* ws = (char*)d_ws;
    float* x0       = (float*)(ws + 0);                           // 2 MB
    float* xb       = (float*)(ws + (2u << 20));                  // 2 MB
    float* kx       = (float*)(ws + (4u << 20));                  // 2 MB
    float* qx       = (float*)(ws + (6u << 20));                  // 2 MB
    int*   csr_v    = (int*)  (ws + (8u << 20));                  // 1 MB
    float* csr_w    = (float*)(ws + (9u << 20));                  // 1 MB
    int2*  vw       = (int2*) (ws + (10u << 20));                 // 2 MB
    int*   deg      = (int*)  (ws + (12u << 20));                 // 32 KB
    int*   bar      = (int*)  (ws + (12u << 20) + (32u << 10));   // 4 B (zeroed w/ deg)
    int*   row_ptr  = (int*)  (ws + (12u << 20) + (64u << 10));   // 32 KB + 4
    int*   row_fill = (int*)  (ws + (12u << 20) + (128u << 10));  // 32 KB

    // zero deg + barrier counter in one memset (contiguous)
    hipMemsetAsync(deg, 0, (32u << 10) + 64, stream);

    enc_k<<<N_ / 16, 256, 0, stream>>>(x_in, enc_w, enc_b, x0);
    kq_k <<<N_ / 16, 256, 0, stream>>>(x0, wk_w, wk_b, wq_w, wq_b, kx, qx);
    count_k<<<(E + 255) / 256, 256, 0, stream>>>(edges, deg, E);
    scan_k<<<1, 256, 0, stream>>>(deg, row_ptr, row_fill);
    score_place_k<<<(E * 16 + 255) / 256, 256, 0, stream>>>(edges, kx, qx, row_fill, csr_v, csr_w, E);
    dedup_k<<<N_ / 4, 256, 0, stream>>>(row_ptr, csr_v, csr_w, vw);

    steps_k<<<256, 1024, 0, stream>>>(x0, xb, row_ptr, vw, dec_w, dec_b, out, bar);
}

// Round 4
// 315.930 us; speedup vs baseline: 1.7325x; 1.7325x over previous
//
#include <hip/hip_runtime.h>
#include <hip/hip_bf16.h>

// N=8192, D_IN=128, H=64, C=40, E=262144, TAU=0.25, T=4 -> 16 steps.
constexpr int N_   = 8192;
constexpr int DIN_ = 128;
constexpr int H_   = 64;
constexpr int C_   = 40;
constexpr int STEPS_ = 16;
#define TAU_ 0.25f

// ---------------- front-end ----------------

__global__ __launch_bounds__(256) void enc_k(const float* __restrict__ xin,
    const float* __restrict__ w, const float* __restrict__ b,
    float* __restrict__ x0)
{
    int wid  = (blockIdx.x * 256 + threadIdx.x) >> 6;
    int lane = threadIdx.x & 63;
    int r0 = wid * 4;
    if (r0 >= N_) return;
    const float* xr = xin + (size_t)r0 * DIN_;
    float bv = b[lane];
    float a0 = bv, a1 = bv, a2 = bv, a3 = bv;
    for (int k = 0; k < DIN_; ++k) {
        float wv = w[k * H_ + lane];
        a0 = fmaf(xr[k],            wv, a0);
        a1 = fmaf(xr[DIN_ + k],     wv, a1);
        a2 = fmaf(xr[2 * DIN_ + k], wv, a2);
        a3 = fmaf(xr[3 * DIN_ + k], wv, a3);
    }
    float* o = x0 + (size_t)r0 * H_ + lane;
    o[0] = a0; o[H_] = a1; o[2 * H_] = a2; o[3 * H_] = a3;
}

__global__ __launch_bounds__(256) void kq_k(const float* __restrict__ x0,
    const float* __restrict__ wk, const float* __restrict__ kb,
    const float* __restrict__ wq, const float* __restrict__ qb,
    float* __restrict__ kx, float* __restrict__ qx)
{
    int wid  = (blockIdx.x * 256 + threadIdx.x) >> 6;
    int lane = threadIdx.x & 63;
    int r0 = wid * 4;
    if (r0 >= N_) return;
    const float* xr = x0 + (size_t)r0 * H_;
    float kbv = kb[lane], qbv = qb[lane];
    float ak0 = kbv, ak1 = kbv, ak2 = kbv, ak3 = kbv;
    float aq0 = qbv, aq1 = qbv, aq2 = qbv, aq3 = qbv;
    for (int k = 0; k < H_; ++k) {
        float wkv = wk[k * H_ + lane];
        float wqv = wq[k * H_ + lane];
        float x0v = xr[k], x1v = xr[H_ + k], x2v = xr[2 * H_ + k], x3v = xr[3 * H_ + k];
        ak0 = fmaf(x0v, wkv, ak0);  aq0 = fmaf(x0v, wqv, aq0);
        ak1 = fmaf(x1v, wkv, ak1);  aq1 = fmaf(x1v, wqv, aq1);
        ak2 = fmaf(x2v, wkv, ak2);  aq2 = fmaf(x2v, wqv, aq2);
        ak3 = fmaf(x3v, wkv, ak3);  aq3 = fmaf(x3v, wqv, aq3);
    }
    float* ok = kx + (size_t)r0 * H_ + lane;
    float* oq = qx + (size_t)r0 * H_ + lane;
    ok[0] = ak0; ok[H_] = ak1; ok[2 * H_] = ak2; ok[3 * H_] = ak3;
    oq[0] = aq0; oq[H_] = aq1; oq[2 * H_] = aq2; oq[3 * H_] = aq3;
}

__global__ __launch_bounds__(256) void count_k(const int2* __restrict__ edges,
    int* __restrict__ deg, int E)
{
    int e = blockIdx.x * 256 + threadIdx.x;
    if (e >= E) return;
    atomicAdd(&deg[edges[e].x], 1);
}

__global__ __launch_bounds__(256) void scan_k(const int* __restrict__ deg,
    int* __restrict__ row_ptr, int* __restrict__ row_fill)
{
    __shared__ int partial[257];
    int t = threadIdx.x;
    const int chunk = N_ / 256;
    int base = t * chunk;
    int s = 0;
    for (int i = 0; i < chunk; ++i) s += deg[base + i];
    partial[t] = s;
    __syncthreads();
    if (t == 0) {
        int run = 0;
        for (int i = 0; i < 256; ++i) { int tmp = partial[i]; partial[i] = run; run += tmp; }
        partial[256] = run;
    }
    __syncthreads();
    int run = partial[t];
    for (int i = 0; i < chunk; ++i) {
        row_ptr[base + i] = run;
        row_fill[base + i] = run;
        run += deg[base + i];
    }
    if (t == 255) row_ptr[N_] = run;
}

__global__ __launch_bounds__(256) void score_place_k(const int2* __restrict__ edges,
    const float* __restrict__ kx, const float* __restrict__ qx,
    int* __restrict__ row_fill, int* __restrict__ csr_v, float* __restrict__ csr_w, int E)
{
    int t  = blockIdx.x * 256 + threadIdx.x;
    int eg = t >> 4;
    int sl = t & 15;
    if (eg >= E) return;
    int2 uv = edges[eg];
    float4 a = ((const float4*)(kx + (size_t)uv.x * H_))[sl];
    float4 b = ((const float4*)(qx + (size_t)uv.y * H_))[sl];
    float d = a.x * b.x + a.y * b.y + a.z * b.z + a.w * b.w;
    d += __shfl_xor(d, 1);
    d += __shfl_xor(d, 2);
    d += __shfl_xor(d, 4);
    d += __shfl_xor(d, 8);
    if (sl == 0) {
        float w = expf(d * (1.0f / (float)H_));
        int pos = atomicAdd(&row_fill[uv.x], 1);
        csr_v[pos] = uv.y;
        csr_w[pos] = w;
    }
}

__global__ __launch_bounds__(256) void dedup_k(const int* __restrict__ row_ptr,
    const int* __restrict__ csr_v, const float* __restrict__ csr_w,
    int2* __restrict__ vw)
{
    __shared__ unsigned int bm[4][256];   // 8192 bits per wave
    int wv   = threadIdx.x >> 6;
    int lane = threadIdx.x & 63;
    int row  = blockIdx.x * 4 + wv;
    unsigned int* b = bm[wv];
    for (int i = lane; i < 256; i += 64) b[i] = 0;
    __syncthreads();
    int p0 = row_ptr[row], p1 = row_ptr[row + 1];
    float wsum = 0.f;
    for (int p = p0 + lane; p < p1; p += 64) {
        int v = csr_v[p];
        unsigned int m = 1u << (v & 31);
        unsigned int old = atomicOr(&b[v >> 5], m);
        float w = (old & m) ? 0.0f : csr_w[p];
        vw[p] = make_int2(v, __float_as_int(w));
        wsum += w;
    }
    #pragma unroll
    for (int off = 1; off < 64; off <<= 1) wsum += __shfl_xor(wsum, off);
    if (p0 == p1) return;                  // empty row
    float scale = TAU_ / wsum;
    for (int p = p0 + lane; p < p1; p += 64) {
        int2 e = vw[p];
        e.y = __float_as_int(__int_as_float(e.y) * scale);
        vw[p] = e;
    }
}

// ---------------- propagation step ----------------
// y = 0.75*x + sum_e w_e * x[v_e]. One wave per row; lane = column. The (v,w)
// list is fetched in ONE coalesced 8B/lane load; entries broadcast via
// constant-index shfl (readlane). Gathers are double-buffered in explicit
// register groups g0/g1 (16 each): group k+1's loads issue before group k's
// fmas -> up to 32 independent 256B gathers in flight per wave.
#define LOADG(gbuf, off)                                                  \
    _Pragma("unroll")                                                     \
    for (int j = 0; j < 16; ++j) {                                        \
        int v = __shfl(e.x, (off) + j);                                   \
        gbuf[j] = x[(size_t)v * H_ + lane];                               \
    }
#define FMAG(gbuf, off)                                                   \
    _Pragma("unroll")                                                     \
    for (int j = 0; j < 16; ++j) {                                        \
        float w = __int_as_float(__shfl(e.y, (off) + j));                 \
        acc = fmaf(w, gbuf[j], acc);                                      \
    }

__global__ __launch_bounds__(256) void step_k(const float* __restrict__ x,
    float* __restrict__ y, const int* __restrict__ row_ptr,
    const int2* __restrict__ vw)
{
    int row  = (blockIdx.x * 256 + threadIdx.x) >> 6;
    int lane = threadIdx.x & 63;
    int p0 = row_ptr[row], p1 = row_ptr[row + 1];   // wave-uniform
    float acc = (1.0f - TAU_) * x[(size_t)row * H_ + lane];
    for (int base = p0; base < p1; base += 64) {
        int rem = p1 - base;                         // wave-uniform, > 0
        int2 e = (lane < rem) ? vw[base + lane] : make_int2(0, 0);
        float g0[16], g1[16];
        // padded lanes inside an active 16-group gather x[0] (L1-hot) with w=0.
        LOADG(g0, 0);
        if (rem > 16) { LOADG(g1, 16); }
        FMAG(g0, 0);
        if (rem > 16) {
            if (rem > 32) { LOADG(g0, 32); }
            FMAG(g1, 16);
            if (rem > 32) {
                if (rem > 48) { LOADG(g1, 48); }
                FMAG(g0, 32);
                if (rem > 48) { FMAG(g1, 48); }
            }
        }
    }
    y[(size_t)row * H_ + lane] = acc;
}

// out = x @ dec_w + dec_b  (N x 64 @ 64 x 40). Wave = 4 rows, lanes 0..39.
__global__ __launch_bounds__(256) void dec_k(const float* __restrict__ x,
    const float* __restrict__ dw, const float* __restrict__ db,
    float* __restrict__ out)
{
    int wid  = (blockIdx.x * 256 + threadIdx.x) >> 6;
    int lane = threadIdx.x & 63;
    int r0 = wid * 4;
    if (r0 >= N_ || lane >= C_) return;
    float bv = db[lane];
    float a0 = bv, a1 = bv, a2 = bv, a3 = bv;
    const float* xr = x + (size_t)r0 * H_;
    for (int k = 0; k < H_; ++k) {
        float dv = dw[k * C_ + lane];
        a0 = fmaf(xr[k],          dv, a0);
        a1 = fmaf(xr[H_ + k],     dv, a1);
        a2 = fmaf(xr[2 * H_ + k], dv, a2);
        a3 = fmaf(xr[3 * H_ + k], dv, a3);
    }
    out[(size_t)r0 * C_ + lane]       = a0;
    out[(size_t)(r0 + 1) * C_ + lane] = a1;
    out[(size_t)(r0 + 2) * C_ + lane] = a2;
    out[(size_t)(r0 + 3) * C_ + lane] = a3;
}

extern "C" void kernel_launch(void* const* d_in, const int* in_sizes, int n_in,
                              void* d_out, int out_size, void* d_ws, size_t ws_size,
                              hipStream_t stream)
{
    const float* x_in  = (const float*)d_in[0];
    const float* enc_w = (const float*)d_in[1];
    const float* enc_b = (const float*)d_in[2];
    const float* wk_w  = (const float*)d_in[3];
    const float* wk_b  = (const float*)d_in[4];
    const float* wq_w  = (const float*)d_in[5];
    const float* wq_b  = (const float*)d_in[6];
    const float* dec_w = (const float*)d_in[7];
    const float* dec_b = (const float*)d_in[8];
    const int2*  edges = (const int2*)d_in[9];
    const int E = in_sizes[9] / 2;   // 262144
    float* out = (float*)d_out;

    char* ws = (char*)d_ws;
    float* x0       = (float*)(ws + 0);                           // 2 MB
    float* xb       = (float*)(ws + (2u << 20));                  // 2 MB
    float* kx       = (float*)(ws + (4u << 20));                  // 2 MB
    float* qx       = (float*)(ws + (6u << 20));                  // 2 MB
    int*   csr_v    = (int*)  (ws + (8u << 20));                  // 1 MB
    float* csr_w    = (float*)(ws + (9u << 20));                  // 1 MB
    int2*  vw       = (int2*) (ws + (10u << 20));                 // 2 MB
    int*   deg      = (int*)  (ws + (12u << 20));                 // 32 KB
    int*   row_ptr  = (int*)  (ws + (12u << 20) + (64u << 10));   // 32 KB + 4
    int*   row_fill = (int*)  (ws + (12u << 20) + (128u << 10));  // 32 KB

    hipMemsetAsync(deg, 0, N_ * sizeof(int), stream);

    enc_k<<<N_ / 16, 256, 0, stream>>>(x_in, enc_w, enc_b, x0);
    kq_k <<<N_ / 16, 256, 0, stream>>>(x0, wk_w, wk_b, wq_w, wq_b, kx, qx);
    count_k<<<(E + 255) / 256, 256, 0, stream>>>(edges, deg, E);
    scan_k<<<1, 256, 0, stream>>>(deg, row_ptr, row_fill);
    score_place_k<<<(E * 16 + 255) / 256, 256, 0, stream>>>(edges, kx, qx, row_fill, csr_v, csr_w, E);
    dedup_k<<<N_ / 4, 256, 0, stream>>>(row_ptr, csr_v, csr_w, vw);

    float* xa = x0;
    for (int s = 0; s < STEPS_; ++s) {
        step_k<<<N_ / 4, 256, 0, stream>>>(xa, (xa == x0) ? xb : x0, row_ptr, vw);
        xa = (xa == x0) ? xb : x0;
    }
    dec_k<<<N_ / 16, 256, 0, stream>>>(xa, dec_w, dec_b, out);
}

// Round 5
// 239.464 us; speedup vs baseline: 2.2857x; 1.3193x over previous
//
#include <hip/hip_runtime.h>
#include <hip/hip_bf16.h>

// N=8192, D_IN=128, H=64, C=40, E=262144, TAU=0.25, T=4 -> 16 steps.
constexpr int N_   = 8192;
constexpr int DIN_ = 128;
constexpr int H_   = 64;
constexpr int C_   = 40;
constexpr int STEPS_ = 16;
#define TAU_ 0.25f

// ---------------- front-end (R2 versions — R4's step experiment reverted) ----

__global__ __launch_bounds__(256) void enc_k(const float* __restrict__ xin,
    const float* __restrict__ w, const float* __restrict__ b,
    float* __restrict__ x0)
{
    int wid  = (blockIdx.x * 256 + threadIdx.x) >> 6;
    int lane = threadIdx.x & 63;
    int r0 = wid * 4;
    if (r0 >= N_) return;
    const float* xr = xin + (size_t)r0 * DIN_;
    float bv = b[lane];
    float a0 = bv, a1 = bv, a2 = bv, a3 = bv;
    for (int k = 0; k < DIN_; ++k) {
        float wv = w[k * H_ + lane];
        a0 = fmaf(xr[k],            wv, a0);
        a1 = fmaf(xr[DIN_ + k],     wv, a1);
        a2 = fmaf(xr[2 * DIN_ + k], wv, a2);
        a3 = fmaf(xr[3 * DIN_ + k], wv, a3);
    }
    float* o = x0 + (size_t)r0 * H_ + lane;
    o[0] = a0; o[H_] = a1; o[2 * H_] = a2; o[3 * H_] = a3;
}

__global__ __launch_bounds__(256) void kq_k(const float* __restrict__ x0,
    const float* __restrict__ wk, const float* __restrict__ kb,
    const float* __restrict__ wq, const float* __restrict__ qb,
    float* __restrict__ kx, float* __restrict__ qx)
{
    int wid  = (blockIdx.x * 256 + threadIdx.x) >> 6;
    int lane = threadIdx.x & 63;
    int r0 = wid * 4;
    if (r0 >= N_) return;
    const float* xr = x0 + (size_t)r0 * H_;
    float kbv = kb[lane], qbv = qb[lane];
    float ak0 = kbv, ak1 = kbv, ak2 = kbv, ak3 = kbv;
    float aq0 = qbv, aq1 = qbv, aq2 = qbv, aq3 = qbv;
    for (int k = 0; k < H_; ++k) {
        float wkv = wk[k * H_ + lane];
        float wqv = wq[k * H_ + lane];
        float x0v = xr[k], x1v = xr[H_ + k], x2v = xr[2 * H_ + k], x3v = xr[3 * H_ + k];
        ak0 = fmaf(x0v, wkv, ak0);  aq0 = fmaf(x0v, wqv, aq0);
        ak1 = fmaf(x1v, wkv, ak1);  aq1 = fmaf(x1v, wqv, aq1);
        ak2 = fmaf(x2v, wkv, ak2);  aq2 = fmaf(x2v, wqv, aq2);
        ak3 = fmaf(x3v, wkv, ak3);  aq3 = fmaf(x3v, wqv, aq3);
    }
    float* ok = kx + (size_t)r0 * H_ + lane;
    float* oq = qx + (size_t)r0 * H_ + lane;
    ok[0] = ak0; ok[H_] = ak1; ok[2 * H_] = ak2; ok[3 * H_] = ak3;
    oq[0] = aq0; oq[H_] = aq1; oq[2 * H_] = aq2; oq[3 * H_] = aq3;
}

__global__ __launch_bounds__(256) void count_k(const int2* __restrict__ edges,
    int* __restrict__ deg, int E)
{
    int e = blockIdx.x * 256 + threadIdx.x;
    if (e >= E) return;
    atomicAdd(&deg[edges[e].x], 1);
}

__global__ __launch_bounds__(256) void scan_k(const int* __restrict__ deg,
    int* __restrict__ row_ptr, int* __restrict__ row_fill)
{
    __shared__ int partial[257];
    int t = threadIdx.x;
    const int chunk = N_ / 256;
    int base = t * chunk;
    int s = 0;
    for (int i = 0; i < chunk; ++i) s += deg[base + i];
    partial[t] = s;
    __syncthreads();
    if (t == 0) {
        int run = 0;
        for (int i = 0; i < 256; ++i) { int tmp = partial[i]; partial[i] = run; run += tmp; }
        partial[256] = run;
    }
    __syncthreads();
    int run = partial[t];
    for (int i = 0; i < chunk; ++i) {
        row_ptr[base + i] = run;
        row_fill[base + i] = run;
        run += deg[base + i];
    }
    if (t == 255) row_ptr[N_] = run;
}

__global__ __launch_bounds__(256) void score_place_k(const int2* __restrict__ edges,
    const float* __restrict__ kx, const float* __restrict__ qx,
    int* __restrict__ row_fill, int* __restrict__ csr_v, float* __restrict__ csr_w, int E)
{
    int t  = blockIdx.x * 256 + threadIdx.x;
    int eg = t >> 4;
    int sl = t & 15;
    if (eg >= E) return;
    int2 uv = edges[eg];
    float4 a = ((const float4*)(kx + (size_t)uv.x * H_))[sl];
    float4 b = ((const float4*)(qx + (size_t)uv.y * H_))[sl];
    float d = a.x * b.x + a.y * b.y + a.z * b.z + a.w * b.w;
    d += __shfl_xor(d, 1);
    d += __shfl_xor(d, 2);
    d += __shfl_xor(d, 4);
    d += __shfl_xor(d, 8);
    if (sl == 0) {
        float w = expf(d * (1.0f / (float)H_));
        int pos = atomicAdd(&row_fill[uv.x], 1);
        csr_v[pos] = uv.y;
        csr_w[pos] = w;
    }
}

__global__ __launch_bounds__(256) void dedup_k(const int* __restrict__ row_ptr,
    const int* __restrict__ csr_v, const float* __restrict__ csr_w,
    int2* __restrict__ vw)
{
    __shared__ unsigned int bm[4][256];   // 8192 bits per wave
    int wv   = threadIdx.x >> 6;
    int lane = threadIdx.x & 63;
    int row  = blockIdx.x * 4 + wv;
    unsigned int* b = bm[wv];
    for (int i = lane; i < 256; i += 64) b[i] = 0;
    __syncthreads();
    int p0 = row_ptr[row], p1 = row_ptr[row + 1];
    float wsum = 0.f;
    for (int p = p0 + lane; p < p1; p += 64) {
        int v = csr_v[p];
        unsigned int m = 1u << (v & 31);
        unsigned int old = atomicOr(&b[v >> 5], m);
        float w = (old & m) ? 0.0f : csr_w[p];
        vw[p] = make_int2(v, __float_as_int(w));
        wsum += w;
    }
    #pragma unroll
    for (int off = 1; off < 64; off <<= 1) wsum += __shfl_xor(wsum, off);
    if (p0 == p1) return;                  // empty row
    float scale = TAU_ / wsum;
    for (int p = p0 + lane; p < p1; p += 64) {
        int2 e = vw[p];
        e.y = __float_as_int(__int_as_float(e.y) * scale);
        vw[p] = e;
    }
}

// ---------------- propagation step: 4 edges / wave-instruction ----------------
// Wave = one row. Lane L: edge-group g=L>>4, columns 4*(L&15)..+3.
// Per 16-edge chunk: 4 int2 loads (16-lane broadcast each) + 4 float4 gathers
// (ONE dwordx4 instr covers 4 edges across the wave) + 16 fma. No shfl in the
// loop. Dummy slots (v,w)=(0,0): w=0 exact, x[0] stays L1-hot.
// Epilogue: shfl_xor(16,32) reduce across the 4 groups; group 0 adds 0.75*x
// and stores the row as 16 float4s.
__global__ __launch_bounds__(256) void step_k(const float* __restrict__ x,
    float* __restrict__ y, const int* __restrict__ row_ptr,
    const int2* __restrict__ vw)
{
    int row  = (blockIdx.x * 256 + threadIdx.x) >> 6;
    int lane = threadIdx.x & 63;
    int grp  = lane >> 4;
    int col4 = lane & 15;
    int p0 = row_ptr[row], p1 = row_ptr[row + 1];   // wave-uniform
    float4 acc = make_float4(0.f, 0.f, 0.f, 0.f);
    for (int base = p0; base < p1; base += 16) {
        int i0 = base + grp, i1 = i0 + 4, i2 = i0 + 8, i3 = i0 + 12;
        int2 e0 = (i0 < p1) ? vw[i0] : make_int2(0, 0);
        int2 e1 = (i1 < p1) ? vw[i1] : make_int2(0, 0);
        int2 e2 = (i2 < p1) ? vw[i2] : make_int2(0, 0);
        int2 e3 = (i3 < p1) ? vw[i3] : make_int2(0, 0);
        float4 g0 = ((const float4*)(x + ((size_t)e0.x << 6)))[col4];
        float4 g1 = ((const float4*)(x + ((size_t)e1.x << 6)))[col4];
        float4 g2 = ((const float4*)(x + ((size_t)e2.x << 6)))[col4];
        float4 g3 = ((const float4*)(x + ((size_t)e3.x << 6)))[col4];
        float w0 = __int_as_float(e0.y), w1 = __int_as_float(e1.y);
        float w2 = __int_as_float(e2.y), w3 = __int_as_float(e3.y);
        acc.x = fmaf(w0, g0.x, acc.x); acc.y = fmaf(w0, g0.y, acc.y);
        acc.z = fmaf(w0, g0.z, acc.z); acc.w = fmaf(w0, g0.w, acc.w);
        acc.x = fmaf(w1, g1.x, acc.x); acc.y = fmaf(w1, g1.y, acc.y);
        acc.z = fmaf(w1, g1.z, acc.z); acc.w = fmaf(w1, g1.w, acc.w);
        acc.x = fmaf(w2, g2.x, acc.x); acc.y = fmaf(w2, g2.y, acc.y);
        acc.z = fmaf(w2, g2.z, acc.z); acc.w = fmaf(w2, g2.w, acc.w);
        acc.x = fmaf(w3, g3.x, acc.x); acc.y = fmaf(w3, g3.y, acc.y);
        acc.z = fmaf(w3, g3.z, acc.z); acc.w = fmaf(w3, g3.w, acc.w);
    }
    // reduce the 4 edge-groups
    acc.x += __shfl_xor(acc.x, 16); acc.y += __shfl_xor(acc.y, 16);
    acc.z += __shfl_xor(acc.z, 16); acc.w += __shfl_xor(acc.w, 16);
    acc.x += __shfl_xor(acc.x, 32); acc.y += __shfl_xor(acc.y, 32);
    acc.z += __shfl_xor(acc.z, 32); acc.w += __shfl_xor(acc.w, 32);
    if (grp == 0) {
        float4 xr = ((const float4*)(x + ((size_t)row << 6)))[col4];
        float4 r;
        r.x = fmaf(1.0f - TAU_, xr.x, acc.x);
        r.y = fmaf(1.0f - TAU_, xr.y, acc.y);
        r.z = fmaf(1.0f - TAU_, xr.z, acc.z);
        r.w = fmaf(1.0f - TAU_, xr.w, acc.w);
        ((float4*)(y + ((size_t)row << 6)))[col4] = r;
    }
}

// out = x @ dec_w + dec_b  (N x 64 @ 64 x 40). Wave = 4 rows, lanes 0..39.
__global__ __launch_bounds__(256) void dec_k(const float* __restrict__ x,
    const float* __restrict__ dw, const float* __restrict__ db,
    float* __restrict__ out)
{
    int wid  = (blockIdx.x * 256 + threadIdx.x) >> 6;
    int lane = threadIdx.x & 63;
    int r0 = wid * 4;
    if (r0 >= N_ || lane >= C_) return;
    float bv = db[lane];
    float a0 = bv, a1 = bv, a2 = bv, a3 = bv;
    const float* xr = x + (size_t)r0 * H_;
    for (int k = 0; k < H_; ++k) {
        float dv = dw[k * C_ + lane];
        a0 = fmaf(xr[k],          dv, a0);
        a1 = fmaf(xr[H_ + k],     dv, a1);
        a2 = fmaf(xr[2 * H_ + k], dv, a2);
        a3 = fmaf(xr[3 * H_ + k], dv, a3);
    }
    out[(size_t)r0 * C_ + lane]       = a0;
    out[(size_t)(r0 + 1) * C_ + lane] = a1;
    out[(size_t)(r0 + 2) * C_ + lane] = a2;
    out[(size_t)(r0 + 3) * C_ + lane] = a3;
}

extern "C" void kernel_launch(void* const* d_in, const int* in_sizes, int n_in,
                              void* d_out, int out_size, void* d_ws, size_t ws_size,
                              hipStream_t stream)
{
    const float* x_in  = (const float*)d_in[0];
    const float* enc_w = (const float*)d_in[1];
    const float* enc_b = (const float*)d_in[2];
    const float* wk_w  = (const float*)d_in[3];
    const float* wk_b  = (const float*)d_in[4];
    const float* wq_w  = (const float*)d_in[5];
    const float* wq_b  = (const float*)d_in[6];
    const float* dec_w = (const float*)d_in[7];
    const float* dec_b = (const float*)d_in[8];
    const int2*  edges = (const int2*)d_in[9];
    const int E = in_sizes[9] / 2;   // 262144
    float* out = (float*)d_out;

    char* ws = (char*)d_ws;
    float* x0       = (float*)(ws + 0);                           // 2 MB
    float* xb       = (float*)(ws + (2u << 20));                  // 2 MB
    float* kx       = (float*)(ws + (4u << 20));                  // 2 MB
    float* qx       = (float*)(ws + (6u << 20));                  // 2 MB
    int*   csr_v    = (int*)  (ws + (8u << 20));                  // 1 MB
    float* csr_w    = (float*)(ws + (9u << 20));                  // 1 MB
    int2*  vw       = (int2*) (ws + (10u << 20));                 // 2 MB
    int*   deg      = (int*)  (ws + (12u << 20));                 // 32 KB
    int*   row_ptr  = (int*)  (ws + (12u << 20) + (64u << 10));   // 32 KB + 4
    int*   row_fill = (int*)  (ws + (12u << 20) + (128u << 10));  // 32 KB

    hipMemsetAsync(deg, 0, N_ * sizeof(int), stream);

    enc_k<<<N_ / 16, 256, 0, stream>>>(x_in, enc_w, enc_b, x0);
    kq_k <<<N_ / 16, 256, 0, stream>>>(x0, wk_w, wk_b, wq_w, wq_b, kx, qx);
    count_k<<<(E + 255) / 256, 256, 0, stream>>>(edges, deg, E);
    scan_k<<<1, 256, 0, stream>>>(deg, row_ptr, row_fill);
    score_place_k<<<(E * 16 + 255) / 256, 256, 0, stream>>>(edges, kx, qx, row_fill, csr_v, csr_w, E);
    dedup_k<<<N_ / 4, 256, 0, stream>>>(row_ptr, csr_v, csr_w, vw);

    float* xa = x0;
    for (int s = 0; s < STEPS_; ++s) {
        step_k<<<N_ / 4, 256, 0, stream>>>(xa, (xa == x0) ? xb : x0, row_ptr, vw);
        xa = (xa == x0) ? xb : x0;
    }
    dec_k<<<N_ / 16, 256, 0, stream>>>(xa, dec_w, dec_b, out);
}